// Round 1
// baseline (709.427 us; speedup 1.0000x reference)
//
#include <hip/hip_runtime.h>

typedef unsigned short ushort_t;
typedef unsigned short ushort8 __attribute__((ext_vector_type(8)));
typedef unsigned short ushort4v __attribute__((ext_vector_type(4)));
typedef __bf16 bf16x8 __attribute__((ext_vector_type(8)));
typedef float f32x4 __attribute__((ext_vector_type(4)));

__device__ __forceinline__ unsigned short f2bf(float f){
  union { float f; unsigned int u; } v; v.f = f;
  unsigned int u = v.u;
  u += 0x7fffu + ((u >> 16) & 1u);   // round-to-nearest-even
  return (unsigned short)(u >> 16);
}
__device__ __forceinline__ float bf2f(unsigned short b){
  union { float f; unsigned int u; } v; v.u = ((unsigned int)b) << 16;
  return v.f;
}
__device__ __forceinline__ float fsilu(float x){
  return x * __builtin_amdgcn_rcpf(1.0f + __expf(-x));
}

// ---------------- K0: convert+transpose weights to bf16 ----------------
// wt layout (ushort units): [0..16383]=Ww1t, [16384..]=Wf1t, [32768..]=Wf2t,
// each stored as Wt[n][k] = W[k][n] so MFMA B-fragments read contiguous k.
__global__ void k0_prep(const float* __restrict__ Wf1, const float* __restrict__ Wf2,
                        const float* __restrict__ Ww1, ushort_t* __restrict__ wt)
{
  int idx = blockIdx.x * 256 + threadIdx.x;     // grid = 192 blocks exactly
  int mtx = idx >> 14, rem = idx & 16383;
  int n = rem >> 7, k = rem & 127;
  const float* src = (mtx == 0) ? Ww1 : (mtx == 1) ? Wf1 : Wf2;
  wt[idx] = f2bf(src[k*128 + n]);
}

// ---------------- K1: fused per-node MLPs ----------------
// Block = 256 thr (4 waves), tile = 128 nodes. Each wave owns 32 rows x 128 cols.
// LDS tiles are bf16, XOR-swizzled at 16B-chunk granularity: chunk' = chunk ^ (row&7).
__global__ __launch_bounds__(256, 2)
void k1_mlp(const float* __restrict__ X, const ushort_t* __restrict__ Wt,
            const float* __restrict__ bf1, const float* __restrict__ bf2,
            const float* __restrict__ bw1, const float* __restrict__ ww2,
            const float* __restrict__ bw2,
            ushort_t* __restrict__ pf, float* __restrict__ wout)
{
  __shared__ ushort_t Xs[128*128];   // X tile, later H tile, later pf staging
  __shared__ ushort_t Ws[128*128];   // current weight matrix (transposed)
  const int tid = threadIdx.x;
  const int lane = tid & 63;
  const int wv = tid >> 6;
  const int cbase = lane & 15;       // row/col within 16x16 fragment
  const int kq = lane >> 4;          // k-group 0..3
  const long r0 = (long)blockIdx.x * 128;
  const int wrow0 = wv * 32;

  // per-lane bias/vector preloads (index = fn*16 + cbase)
  float vbw1[8], vbf1[8], vbf2[8], vww2[8];
#pragma unroll
  for (int f = 0; f < 8; f++){
    vbw1[f] = bw1[f*16+cbase];
    vbf1[f] = bf1[f*16+cbase];
    vbf2[f] = bf2[f*16+cbase];
    vww2[f] = ww2[f*16+cbase];
  }
  const float sbw2 = bw2[0];

  // ---- stage X tile: 128x128 f32 -> bf16 swizzled LDS ----
#pragma unroll
  for (int it = 0; it < 16; it++){
    int idx = it*256 + tid;              // 128 rows * 32 float4-chunks
    int row = idx >> 5, c4 = idx & 31;
    const float4 v = *(const float4*)(X + (r0+row)*128 + c4*4);
    ushort4v h;
    h[0]=f2bf(v.x); h[1]=f2bf(v.y); h[2]=f2bf(v.z); h[3]=f2bf(v.w);
    *(ushort4v*)(Xs + row*128 + ((((c4>>1) ^ (row&7))<<3)) + ((c4&1)<<2)) = h;
  }

  auto stage_w = [&](const ushort_t* src){
#pragma unroll
    for (int it = 0; it < 8; it++){
      int idx = it*256 + tid;            // 128 rows * 16 chunks
      int row = idx >> 4, ch = idx & 15;
      ushort8 v = *(const ushort8*)(src + row*128 + ch*8);
      *(ushort8*)(Ws + row*128 + ((ch ^ (row&7))<<3)) = v;
    }
  };

  f32x4 acc[2][8];
  auto zero_acc = [&]{
#pragma unroll
    for (int a=0;a<2;a++)
#pragma unroll
      for (int b=0;b<8;b++) acc[a][b] = (f32x4){0.f,0.f,0.f,0.f};
  };
  // acc[fm][fn] holds 16x16 tile: row = wrow0+fm*16+kq*4+reg, col = fn*16+cbase
  auto gemm = [&]{
#pragma unroll
    for (int ks = 0; ks < 4; ks++){
      bf16x8 av[2], bv[8];
#pragma unroll
      for (int fm = 0; fm < 2; fm++){
        int row = wrow0 + fm*16 + cbase;
        av[fm] = __builtin_bit_cast(bf16x8,
          *(const ushort8*)(Xs + row*128 + (((ks*4+kq) ^ (row&7))<<3)));
      }
#pragma unroll
      for (int fn = 0; fn < 8; fn++){
        int col = fn*16 + cbase;
        bv[fn] = __builtin_bit_cast(bf16x8,
          *(const ushort8*)(Ws + col*128 + (((ks*4+kq) ^ (col&7))<<3)));
      }
#pragma unroll
      for (int fm = 0; fm < 2; fm++)
#pragma unroll
        for (int fn = 0; fn < 8; fn++)
          acc[fm][fn] = __builtin_amdgcn_mfma_f32_16x16x32_bf16(
                          av[fm], bv[fn], acc[fm][fn], 0, 0, 0);
    }
  };

  // ---- weight-path: w = silu(X@Ww1 + bw1) @ Ww2 + bw2 ----
  stage_w(Wt + 0);               // Ww1t
  __syncthreads();
  zero_acc(); gemm();
#pragma unroll
  for (int fm = 0; fm < 2; fm++){
#pragma unroll
    for (int reg = 0; reg < 4; reg++){
      float p = 0.f;
#pragma unroll
      for (int fn = 0; fn < 8; fn++)
        p += fsilu(acc[fm][fn][reg] + vbw1[fn]) * vww2[fn];
      p += __shfl_xor(p, 1); p += __shfl_xor(p, 2);
      p += __shfl_xor(p, 4); p += __shfl_xor(p, 8);
      if (cbase == 0)
        wout[r0 + wrow0 + fm*16 + kq*4 + reg] = p + sbw2;
    }
  }
  __syncthreads();               // all waves done reading Ws (Ww1t)

  // ---- feature-path hidden: H = silu(X@Wf1 + bf1) ----
  stage_w(Wt + 16384);           // Wf1t
  __syncthreads();
  zero_acc(); gemm();
  // write H into own slab of Xs (safe: this wave only reads its own rows)
#pragma unroll
  for (int fm=0;fm<2;fm++)
#pragma unroll
    for (int fn=0;fn<8;fn++)
#pragma unroll
      for (int reg=0;reg<4;reg++){
        int row = wrow0 + fm*16 + kq*4 + reg;
        int col = fn*16 + cbase;
        float h = fsilu(acc[fm][fn][reg] + vbf1[fn]);
        Xs[row*128 + ((((col>>3) ^ (row&7))<<3)) + (col&7)] = f2bf(h);
      }
  __syncthreads();               // all waves done reading Ws (Wf1t)

  // ---- pf = H @ Wf2 + bf2 ----
  stage_w(Wt + 32768);           // Wf2t
  __syncthreads();
  zero_acc(); gemm();
  // write pf (bf16) into own slab, then coalesced store to global
#pragma unroll
  for (int fm=0;fm<2;fm++)
#pragma unroll
    for (int fn=0;fn<8;fn++)
#pragma unroll
      for (int reg=0;reg<4;reg++){
        int row = wrow0 + fm*16 + kq*4 + reg;
        int col = fn*16 + cbase;
        Xs[row*128 + ((((col>>3) ^ (row&7))<<3)) + (col&7)]
          = f2bf(acc[fm][fn][reg] + vbf2[fn]);
      }
  __syncthreads();
#pragma unroll
  for (int j = 0; j < 8; j++){
    int flat = j*64 + lane;              // 32 rows * 16 chunks per wave slab
    int rsl = flat >> 4, ch = flat & 15;
    int row = wrow0 + rsl;
    ushort8 v = *(const ushort8*)(Xs + row*128 + ((ch ^ (row&7))<<3));
    *(ushort8*)(pf + (r0+row)*128 + ch*8) = v;
  }
}

// ---------------- K2: per-graph softmax pool ----------------
__device__ __forceinline__ int lbound(const int* __restrict__ a, int n, int v){
  int lo = 0, hi = n;
  while (lo < hi){
    int mid = (lo + hi) >> 1;
    if (a[mid] < v) lo = mid + 1; else hi = mid;
  }
  return lo;
}

__global__ __launch_bounds__(256)
void k2_pool(const float* __restrict__ w, const ushort_t* __restrict__ pf,
             const int* __restrict__ seg, float* __restrict__ out, int Nn)
{
  __shared__ int sse[2];
  __shared__ float sred[512];
  const int tid = threadIdx.x;
  const int g = blockIdx.x;
  if (tid < 2) sse[tid] = lbound(seg, Nn, g + tid);
  __syncthreads();
  const int s = sse[0], e = sse[1];

  // pass 1: segment max
  float m = -3.0e38f;
  for (int i = s + tid; i < e; i += 256) m = fmaxf(m, w[i]);
#pragma unroll
  for (int d = 32; d; d >>= 1) m = fmaxf(m, __shfl_xor(m, d));
  if ((tid & 63) == 0) sred[tid >> 6] = m;
  __syncthreads();
  m = fmaxf(fmaxf(sred[0], sred[1]), fmaxf(sred[2], sred[3]));
  __syncthreads();

  // pass 2: sum of exp
  float ssum = 0.f;
  for (int i = s + tid; i < e; i += 256) ssum += __expf(w[i] - m);
#pragma unroll
  for (int d = 32; d; d >>= 1) ssum += __shfl_xor(ssum, d);
  if ((tid & 63) == 0) sred[tid >> 6] = ssum;
  __syncthreads();
  const float invS = 1.0f / (sred[0] + sred[1] + sred[2] + sred[3] + 1e-16f);
  __syncthreads();

  // pass 3: weighted accumulate of pf rows (4 nodes per iteration)
  float a0 = 0.f, a1 = 0.f;
  const int sub = tid >> 6, pr = tid & 63;   // d-pair = pr*2, pr*2+1
  for (int i = s + sub; i < e; i += 4){
    const float en = __expf(w[i] - m) * invS;
    const unsigned int u = *(const unsigned int*)(pf + (size_t)i*128 + pr*2);
    a0 += en * bf2f((unsigned short)(u & 0xffffu));
    a1 += en * bf2f((unsigned short)(u >> 16));
  }
  sred[tid*2] = a0; sred[tid*2+1] = a1;
  __syncthreads();
  if (tid < 64){
    float r0a = 0.f, r1a = 0.f;
#pragma unroll
    for (int q = 0; q < 4; q++){
      r0a += sred[(q*64+tid)*2];
      r1a += sred[(q*64+tid)*2+1];
    }
    out[(size_t)g*128 + tid*2]     = r0a;
    out[(size_t)g*128 + tid*2 + 1] = r1a;
  }
}

// ---------------- launch ----------------
extern "C" void kernel_launch(void* const* d_in, const int* in_sizes, int n_in,
                              void* d_out, int out_size, void* d_ws, size_t ws_size,
                              hipStream_t stream) {
  const float* X   = (const float*)d_in[0];
  const int*   seg = (const int*)d_in[1];          // sorted batch index
  const float* Wf1 = (const float*)d_in[2];
  const float* bf1 = (const float*)d_in[3];
  const float* Wf2 = (const float*)d_in[4];
  const float* bf2 = (const float*)d_in[5];
  const float* Ww1 = (const float*)d_in[6];
  const float* bw1 = (const float*)d_in[7];
  const float* Ww2 = (const float*)d_in[8];
  const float* bw2 = (const float*)d_in[9];
  float* out = (float*)d_out;

  const int Nn = in_sizes[0] / 128;                // 800000
  const int G  = out_size / 128;                   // 4096

  // workspace layout: pf bf16 [Nn*128], w f32 [Nn], weights bf16 [3*16384]
  ushort_t* pf   = (ushort_t*)d_ws;
  float*    wbuf = (float*)((char*)d_ws + (size_t)Nn*128*2);
  ushort_t* wt   = (ushort_t*)((char*)d_ws + (size_t)Nn*128*2 + (size_t)Nn*4);

  k0_prep<<<192, 256, 0, stream>>>(Wf1, Wf2, Ww1, wt);
  k1_mlp<<<Nn/128, 256, 0, stream>>>(X, wt, bf1, bf2, bw1, Ww2, bw2, pf, wbuf);
  k2_pool<<<G, 256, 0, stream>>>(wbuf, pf, seg, out, Nn);
}

// Round 2
// 668.598 us; speedup vs baseline: 1.0611x; 1.0611x over previous
//
#include <hip/hip_runtime.h>

typedef unsigned short ushort_t;
typedef unsigned short ushort8 __attribute__((ext_vector_type(8)));
typedef unsigned short ushort4v __attribute__((ext_vector_type(4)));
typedef __bf16 bf16x8 __attribute__((ext_vector_type(8)));
typedef float f32x4 __attribute__((ext_vector_type(4)));

__device__ __forceinline__ unsigned short f2bf(float f){
  union { float f; unsigned int u; } v; v.f = f;
  unsigned int u = v.u;
  u += 0x7fffu + ((u >> 16) & 1u);   // round-to-nearest-even
  return (unsigned short)(u >> 16);
}
__device__ __forceinline__ float bf2f(unsigned short b){
  union { float f; unsigned int u; } v; v.u = ((unsigned int)b) << 16;
  return v.f;
}
__device__ __forceinline__ float fsilu(float x){
  return x * __builtin_amdgcn_rcpf(1.0f + __expf(-x));
}

#define GRID1   256
#define WAVES1  8
#define THR1    (WAVES1*64)
#define GWAVES  (GRID1*WAVES1)     // 2048 free-running waves

// ---------------- K0: convert+transpose weights to bf16 ----------------
// wt: [0..16383]=Ww1t, [16384..]=Wf1t, [32768..]=Wf2t, each Wt[n][k]=W[k][n].
__global__ void k0_prep(const float* __restrict__ Wf1, const float* __restrict__ Wf2,
                        const float* __restrict__ Ww1, ushort_t* __restrict__ wt)
{
  int idx = blockIdx.x * 256 + threadIdx.x;     // grid = 192 blocks exactly
  int mtx = idx >> 14, rem = idx & 16383;
  int n = rem >> 7, k = rem & 127;
  const float* src = (mtx == 0) ? Ww1 : (mtx == 1) ? Wf1 : Wf2;
  wt[idx] = f2bf(src[k*128 + n]);
}

// ---------------- K1: fused per-node MLPs, barrier-free persistent waves ----
// LDS: [0..49151] = 3 weight matrices (swizzled), then 8 x 2048-ushort private
// slabs (one 16-row X/H/pf tile per wave). One __syncthreads total.
__global__ __launch_bounds__(THR1, 2)
void k1_mlp(const float* __restrict__ X, const ushort_t* __restrict__ Wt,
            const float* __restrict__ bf1, const float* __restrict__ bf2,
            const float* __restrict__ bw1, const float* __restrict__ ww2,
            const float* __restrict__ bw2,
            ushort_t* __restrict__ pf, float* __restrict__ wout, int C)
{
  __shared__ ushort_t lds[65536];              // 128 KiB
  const int tid   = threadIdx.x;
  const int lane  = tid & 63;
  const int wv    = tid >> 6;
  const int cbase = lane & 15;
  const int kq    = lane >> 4;

  // ---- stage all three weight matrices, swizzled: one barrier ----
  for (int i = tid; i < 6144; i += THR1){      // 384 rows x 16 chunks
    int mrow = i >> 4, ch = i & 15;
    ushort8 v = *(const ushort8*)(Wt + mrow*128 + ch*8);
    *(ushort8*)(lds + mrow*128 + ((ch ^ (mrow & 7)) << 3)) = v;
  }

  // per-lane bias/vector preloads (index = fn*16 + cbase)
  float vbw1[8], vbf1[8], vbf2[8], vww2[8];
#pragma unroll
  for (int f = 0; f < 8; f++){
    vbw1[f] = bw1[f*16+cbase];
    vbf1[f] = bf1[f*16+cbase];
    vbf2[f] = bf2[f*16+cbase];
    vww2[f] = ww2[f*16+cbase];
  }
  const float sbw2 = bw2[0];

  __syncthreads();                             // weights resident; free-run now

  ushort_t* slab = lds + 49152 + wv*2048;      // private 16x128 bf16 tile

  float4 xr[8];
  auto load_xr = [&](long c){
#pragma unroll
    for (int it = 0; it < 8; it++){
      int idx = it*64 + lane;                  // 16 rows x 32 float4-chunks
      int row = idx >> 5, c4 = idx & 31;
      xr[it] = *(const float4*)(X + (c*16 + row)*128 + c4*4);
    }
  };

  f32x4 acc[8];
  // gemm: acc[fn][reg] = tile[row=kq*4+reg][col=fn*16+cbase] over K=128
  auto gemmv = [&](int mtx){
#pragma unroll
    for (int i = 0; i < 8; i++) acc[i] = (f32x4){0.f,0.f,0.f,0.f};
#pragma unroll
    for (int ks = 0; ks < 4; ks++){
      const int chunkid = ks*4 + kq;
      const int arow = cbase;
      bf16x8 av = __builtin_bit_cast(bf16x8,
        *(const ushort8*)(slab + arow*128 + ((chunkid ^ (arow & 7)) << 3)));
#pragma unroll
      for (int fn = 0; fn < 8; fn++){
        int col = fn*16 + cbase;
        bf16x8 bv = __builtin_bit_cast(bf16x8,
          *(const ushort8*)(lds + mtx*16384 + col*128 + ((chunkid ^ (col & 7)) << 3)));
        acc[fn] = __builtin_amdgcn_mfma_f32_16x16x32_bf16(av, bv, acc[fn], 0, 0, 0);
      }
    }
  };

  const int gw = blockIdx.x * WAVES1 + wv;
  long c = gw;
  if (c < C) load_xr(c);
  for (; c < C; c += GWAVES){
    // convert current X chunk -> private slab (swizzled)
#pragma unroll
    for (int it = 0; it < 8; it++){
      int idx = it*64 + lane;
      int row = idx >> 5, c4 = idx & 31;
      ushort4v h;
      h[0]=f2bf(xr[it].x); h[1]=f2bf(xr[it].y);
      h[2]=f2bf(xr[it].z); h[3]=f2bf(xr[it].w);
      *(ushort4v*)(slab + row*128 + (((c4>>1) ^ (row&7)) << 3) + ((c4&1) << 2)) = h;
    }
    // async prefetch next chunk's X into regs (hides HBM under 3 gemms)
    long cn = c + GWAVES;
    if (cn < C) load_xr(cn);

    // ---- weight path: w = silu(X@Ww1+bw1)@Ww2 + bw2 ----
    gemmv(0);
    {
      f32x4 pr;
#pragma unroll
      for (int reg = 0; reg < 4; reg++){
        float p = 0.f;
#pragma unroll
        for (int fn = 0; fn < 8; fn++)
          p += fsilu(acc[fn][reg] + vbw1[fn]) * vww2[fn];
        pr[reg] = p;
      }
#pragma unroll
      for (int reg = 0; reg < 4; reg++){
        pr[reg] += __shfl_xor(pr[reg], 1); pr[reg] += __shfl_xor(pr[reg], 2);
        pr[reg] += __shfl_xor(pr[reg], 4); pr[reg] += __shfl_xor(pr[reg], 8);
        pr[reg] += sbw2;
      }
      if (cbase == 0)
        *(float4*)(wout + c*16 + kq*4) = (float4){pr[0], pr[1], pr[2], pr[3]};
    }

    // ---- feature hidden: H = silu(X@Wf1+bf1), overwrite own slab ----
    gemmv(1);
#pragma unroll
    for (int fn = 0; fn < 8; fn++)
#pragma unroll
      for (int reg = 0; reg < 4; reg++){
        int row = kq*4 + reg, col = fn*16 + cbase;
        slab[row*128 + ((((col>>3) ^ (row&7)) << 3)) + (col&7)]
          = f2bf(fsilu(acc[fn][reg] + vbf1[fn]));
      }

    // ---- pf = H@Wf2 + bf2 ----
    gemmv(2);
#pragma unroll
    for (int fn = 0; fn < 8; fn++)
#pragma unroll
      for (int reg = 0; reg < 4; reg++){
        int row = kq*4 + reg, col = fn*16 + cbase;
        slab[row*128 + ((((col>>3) ^ (row&7)) << 3)) + (col&7)]
          = f2bf(acc[fn][reg] + vbf2[fn]);
      }
    // coalesced 1 KiB/instr store of the 16x128 bf16 pf tile
#pragma unroll
    for (int j = 0; j < 4; j++){
      int flat = j*64 + lane;
      int row = flat >> 4, ch = flat & 15;
      ushort8 v = *(const ushort8*)(slab + row*128 + ((ch ^ (row&7)) << 3));
      *(ushort8*)(pf + (c*16 + row)*128 + ch*8) = v;
    }
  }
}

// ---------------- K2: per-graph softmax pool (vectorized pass 3) ----------
__device__ __forceinline__ int lbound(const int* __restrict__ a, int n, int v){
  int lo = 0, hi = n;
  while (lo < hi){
    int mid = (lo + hi) >> 1;
    if (a[mid] < v) lo = mid + 1; else hi = mid;
  }
  return lo;
}

__global__ __launch_bounds__(256)
void k2_pool(const float* __restrict__ w, const ushort_t* __restrict__ pf,
             const int* __restrict__ seg, float* __restrict__ out, int Nn)
{
  __shared__ int sse[2];
  __shared__ float sred[4*128];
  const int tid  = threadIdx.x;
  const int g    = blockIdx.x;
  const int wv   = tid >> 6;
  const int lane = tid & 63;
  const int q    = lane >> 4;      // row-quad within wave
  const int cb   = lane & 15;      // 8-wide d-chunk
  if (tid < 2) sse[tid] = lbound(seg, Nn, g + tid);
  __syncthreads();
  const int s = sse[0], e = sse[1];

  // pass 1: segment max
  float m = -3.0e38f;
  for (int i = s + tid; i < e; i += 256) m = fmaxf(m, w[i]);
#pragma unroll
  for (int d = 32; d; d >>= 1) m = fmaxf(m, __shfl_xor(m, d));
  if (lane == 0) sred[wv] = m;
  __syncthreads();
  m = fmaxf(fmaxf(sred[0], sred[1]), fmaxf(sred[2], sred[3]));
  __syncthreads();

  // pass 2: sum of exp
  float ssum = 0.f;
  for (int i = s + tid; i < e; i += 256) ssum += __expf(w[i] - m);
#pragma unroll
  for (int d = 32; d; d >>= 1) ssum += __shfl_xor(ssum, d);
  if (lane == 0) sred[wv] = ssum;
  __syncthreads();
  const float invS = 1.0f / (sred[0] + sred[1] + sred[2] + sred[3] + 1e-16f);
  __syncthreads();

  // pass 3: weighted accumulate, dwordx4 loads (16 rows / block-iter)
  float a[8];
#pragma unroll
  for (int j = 0; j < 8; j++) a[j] = 0.f;
  for (int i = s + wv*4 + q; i < e; i += 16){
    const float en = __expf(w[i] - m) * invS;
    ushort8 v = *(const ushort8*)(pf + (size_t)i*128 + cb*8);
#pragma unroll
    for (int j = 0; j < 8; j++) a[j] += en * bf2f(v[j]);
  }
  // reduce across row-quads (bits 4,5 of lane)
#pragma unroll
  for (int j = 0; j < 8; j++){
    a[j] += __shfl_xor(a[j], 16);
    a[j] += __shfl_xor(a[j], 32);
  }
  if (lane < 16){
#pragma unroll
    for (int j = 0; j < 8; j++) sred[wv*128 + cb*8 + j] = a[j];
  }
  __syncthreads();
  if (tid < 128){
    out[(size_t)g*128 + tid]
      = sred[tid] + sred[128 + tid] + sred[256 + tid] + sred[384 + tid];
  }
}

// ---------------- launch ----------------
extern "C" void kernel_launch(void* const* d_in, const int* in_sizes, int n_in,
                              void* d_out, int out_size, void* d_ws, size_t ws_size,
                              hipStream_t stream) {
  const float* X   = (const float*)d_in[0];
  const int*   seg = (const int*)d_in[1];          // sorted batch index
  const float* Wf1 = (const float*)d_in[2];
  const float* bf1 = (const float*)d_in[3];
  const float* Wf2 = (const float*)d_in[4];
  const float* bf2 = (const float*)d_in[5];
  const float* Ww1 = (const float*)d_in[6];
  const float* bw1 = (const float*)d_in[7];
  const float* Ww2 = (const float*)d_in[8];
  const float* bw2 = (const float*)d_in[9];
  float* out = (float*)d_out;

  const int Nn = in_sizes[0] / 128;                // 800000
  const int G  = out_size / 128;                   // 4096
  const int C  = Nn / 16;                          // 16-row chunks

  // workspace: pf bf16 [Nn*128], w f32 [Nn], weights bf16 [3*16384]
  ushort_t* pf   = (ushort_t*)d_ws;
  float*    wbuf = (float*)((char*)d_ws + (size_t)Nn*128*2);
  ushort_t* wt   = (ushort_t*)((char*)d_ws + (size_t)Nn*128*2 + (size_t)Nn*4);

  k0_prep<<<192, 256, 0, stream>>>(Wf1, Wf2, Ww1, wt);
  k1_mlp<<<GRID1, THR1, 0, stream>>>(X, wt, bf1, bf2, bw1, Ww2, bw2, pf, wbuf, C);
  k2_pool<<<G, 256, 0, stream>>>(wbuf, pf, seg, out, Nn);
}